// Round 1
// 256.944 us; speedup vs baseline: 1.1165x; 1.1165x over previous
//
#include <hip/hip_runtime.h>

// B=8, S=2048, D=1024 banded attention, window +-20.
// out[b,q,:] = softmax_k( q^T W key_k , |q-k|<=20 ) @ keys
// b_reduce: per-q constant on every logit -> cancels in softmax -> unused.
//
// R4: gemm path rebuilt around global_load_lds (m97 structure):
//   cvt_q_f16:  Q fp32 -> f16 (scratch = first 33.5MB of d_out, dead until attn)
//   cvt_w_t  :  W fp32 -> f16, pre-transposed to [n][k] (B^T layout for MFMA)
//   gemm_f16t:  128x128 tile, BK=64, global_load_lds w=16, XOR-swizzled LDS
//               (pre-swizzled global source + matching swizzled ds_read_b128),
//               writes QT as f16 into d_ws (attn rounds to f16 anyway).
//   attn_mfma<T>: unchanged structure, templated to read f16 QT.
// Fallback to the R3 path if ws_size < 35.5 MB.

#define BATCH 8
#define SEQ   2048
#define DIM   1024
#define WIN   20

typedef _Float16 half8  __attribute__((ext_vector_type(8)));
typedef _Float16 half4v __attribute__((ext_vector_type(4)));
typedef float    f32x4  __attribute__((ext_vector_type(4)));

#define GLOAD_LDS16(gsrc, ldst)                                                        \
    __builtin_amdgcn_global_load_lds(                                                  \
        (const __attribute__((address_space(1))) void*)(gsrc),                         \
        (__attribute__((address_space(3))) void*)(ldst), 16, 0, 0)

// ---------------------------------------------------------------------------
// Prep 1: Q fp32 -> f16, vectorized 8/thread, grid-stride.
// ---------------------------------------------------------------------------
__global__ __launch_bounds__(256) void cvt_q_f16(const float* __restrict__ in,
                                                 _Float16* __restrict__ out) {
    const int n8 = (BATCH * SEQ * DIM) / 8;
    for (int i = blockIdx.x * 256 + threadIdx.x; i < n8; i += gridDim.x * 256) {
        const float4 a = ((const float4*)in)[2 * i];
        const float4 b = ((const float4*)in)[2 * i + 1];
        half8 h;
        h[0] = (_Float16)a.x; h[1] = (_Float16)a.y; h[2] = (_Float16)a.z; h[3] = (_Float16)a.w;
        h[4] = (_Float16)b.x; h[5] = (_Float16)b.y; h[6] = (_Float16)b.z; h[7] = (_Float16)b.w;
        ((half8*)out)[i] = h;
    }
}

// ---------------------------------------------------------------------------
// Prep 2: W [k][n] fp32 -> WT [n][k] f16 (LDS tile transpose, 64x64 per block).
// ---------------------------------------------------------------------------
#define WTS 68
__global__ __launch_bounds__(256) void cvt_w_t(const float* __restrict__ W,
                                               _Float16* __restrict__ WT) {
    __shared__ _Float16 tile[64 * WTS];
    const int k0 = blockIdx.x * 64;
    const int n0 = blockIdx.y * 64;
    const int t  = threadIdx.x;
    const int r  = t >> 4;          // 0..15
    const int c4 = (t & 15) * 4;    // 0..60
    #pragma unroll
    for (int rr = 0; rr < 64; rr += 16) {
        float4 v = *(const float4*)&W[(size_t)(k0 + rr + r) * DIM + n0 + c4];
        _Float16* dst = &tile[(rr + r) * WTS + c4];
        dst[0] = (_Float16)v.x; dst[1] = (_Float16)v.y;
        dst[2] = (_Float16)v.z; dst[3] = (_Float16)v.w;
    }
    __syncthreads();
    #pragma unroll
    for (int rr = 0; rr < 64; rr += 16) {
        const int n = rr + r;
        half4v h = { tile[(c4 + 0) * WTS + n], tile[(c4 + 1) * WTS + n],
                     tile[(c4 + 2) * WTS + n], tile[(c4 + 3) * WTS + n] };
        *(half4v*)&WT[(size_t)(n0 + n) * DIM + k0 + c4] = h;
    }
}

// ---------------------------------------------------------------------------
// GEMM: C[m][n] = sum_k A[m][k] * B[n][k], all f16 (fp32 accum), C f16 out.
// M=16384, N=1024, K=1024. 128x128 tile, BK=64, 4 waves (2x2), 256 threads.
// Staging: global_load_lds width=16, linear LDS dest, source chunk
// pre-swizzled by (l&7)^(l>>3); fragment ds_read_b128 applies the same XOR
// -> rows spread across all 32 banks (2-way max = free).
// ---------------------------------------------------------------------------
#define GK 64
__global__ __launch_bounds__(256, 2) void gemm_f16t(const _Float16* __restrict__ A,
                                                    const _Float16* __restrict__ B,
                                                    _Float16* __restrict__ C) {
    __shared__ _Float16 As[128 * GK];   // 16 KB
    __shared__ _Float16 Bs[128 * GK];   // 16 KB

    const int m0   = blockIdx.x * 128;
    const int n0   = blockIdx.y * 128;
    const int t    = threadIdx.x;
    const int lane = t & 63;
    const int wv   = t >> 6;
    const int wm   = (wv >> 1) * 64;
    const int wn   = (wv & 1) * 64;
    const int l15  = lane & 15;
    const int quad = lane >> 4;

    const int srow = lane >> 3;             // 0..7 : row within 8-row group
    const int sck  = (lane & 7) ^ srow;     // swizzled source 16B-chunk

    f32x4 acc[4][4] = {};

    for (int k0 = 0; k0 < DIM; k0 += GK) {
        __syncthreads();   // previous iteration's fragment reads done
        #pragma unroll
        for (int j = 0; j < 4; ++j) {
            const int rs = (j * 4 + wv) * 8;   // wave-uniform 8-row group
            GLOAD_LDS16(A + (size_t)(m0 + rs + srow) * DIM + k0 + sck * 8, &As[rs * GK]);
            GLOAD_LDS16(B + (size_t)(n0 + rs + srow) * DIM + k0 + sck * 8, &Bs[rs * GK]);
        }
        __syncthreads();   // compiler drains vmcnt(0) before the barrier

        #pragma unroll
        for (int s = 0; s < 2; ++s) {
            half8 af[4], bf[4];
            #pragma unroll
            for (int i = 0; i < 4; ++i)
                af[i] = *(const half8*)&As[(wm + i * 16 + l15) * GK +
                                           (((s * 4 + quad) ^ (l15 & 7)) * 8)];
            #pragma unroll
            for (int j = 0; j < 4; ++j)
                bf[j] = *(const half8*)&Bs[(wn + j * 16 + l15) * GK +
                                           (((s * 4 + quad) ^ (l15 & 7)) * 8)];
            #pragma unroll
            for (int i = 0; i < 4; ++i)
                #pragma unroll
                for (int j = 0; j < 4; ++j)
                    acc[i][j] = __builtin_amdgcn_mfma_f32_16x16x32_f16(af[i], bf[j], acc[i][j], 0, 0, 0);
        }
    }

    // C/D layout: col = lane&15, row = quad*4 + reg (dtype-independent)
    #pragma unroll
    for (int i = 0; i < 4; ++i) {
        #pragma unroll
        for (int r = 0; r < 4; ++r) {
            _Float16* crow = C + (size_t)(m0 + wm + i * 16 + quad * 4 + r) * DIM + n0 + wn + l15;
            #pragma unroll
            for (int j = 0; j < 4; ++j)
                crow[j * 16] = (_Float16)acc[i][j][r];
        }
    }
}

// ---------------------------------------------------------------------------
// Fallback GEMM (R3, known good): qt = Q @ W, fp32 in, fp32 out into d_out.
// ---------------------------------------------------------------------------
#define LDK 40
__global__ __launch_bounds__(256) void gemm_qw_f16(const float* __restrict__ Q,
                                                   const float* __restrict__ W,
                                                   float* __restrict__ QT) {
    __shared__ _Float16 Asl[128 * LDK];
    __shared__ _Float16 Bsl[128 * LDK];

    const int m0 = blockIdx.x * 128;
    const int n0 = blockIdx.y * 128;
    const int t  = threadIdx.x;
    const int lane = t & 63;
    const int wv   = t >> 6;
    const int wm   = (wv >> 1) * 64;
    const int wn   = (wv & 1) * 64;
    const int l15  = lane & 15;
    const int quad = lane >> 4;

    const int ar = t >> 1;
    const int ac = (t & 1) * 16;
    const float* Aptr = Q + (size_t)(m0 + ar) * DIM + ac;
    _Float16* AsW = &Asl[ar * LDK + ac];

    const int br = t >> 3;
    const int bc = t & 7;
    const float* Bptr = W + (size_t)br * DIM + n0 + bc;

    f32x4 acc[4][4] = {};

    for (int k0 = 0; k0 < DIM; k0 += 32) {
        float4 a0 = *(const float4*)(Aptr + k0);
        float4 a1 = *(const float4*)(Aptr + k0 + 4);
        float4 a2 = *(const float4*)(Aptr + k0 + 8);
        float4 a3 = *(const float4*)(Aptr + k0 + 12);
        float bv[16];
        #pragma unroll
        for (int j = 0; j < 16; ++j) bv[j] = Bptr[(size_t)k0 * DIM + 8 * j];

        __syncthreads();

        half8 h0, h1;
        h0[0] = (_Float16)a0.x; h0[1] = (_Float16)a0.y; h0[2] = (_Float16)a0.z; h0[3] = (_Float16)a0.w;
        h0[4] = (_Float16)a1.x; h0[5] = (_Float16)a1.y; h0[6] = (_Float16)a1.z; h0[7] = (_Float16)a1.w;
        h1[0] = (_Float16)a2.x; h1[1] = (_Float16)a2.y; h1[2] = (_Float16)a2.z; h1[3] = (_Float16)a2.w;
        h1[4] = (_Float16)a3.x; h1[5] = (_Float16)a3.y; h1[6] = (_Float16)a3.z; h1[7] = (_Float16)a3.w;
        *(half8*)(AsW)     = h0;
        *(half8*)(AsW + 8) = h1;

        #pragma unroll
        for (int j = 0; j < 16; ++j)
            Bsl[(bc + 8 * j) * LDK + br] = (_Float16)bv[j];

        __syncthreads();

        half8 af[4], bf[4];
        #pragma unroll
        for (int i = 0; i < 4; ++i)
            af[i] = *(const half8*)&Asl[(wm + i * 16 + l15) * LDK + quad * 8];
        #pragma unroll
        for (int j = 0; j < 4; ++j)
            bf[j] = *(const half8*)&Bsl[(wn + j * 16 + l15) * LDK + quad * 8];

        #pragma unroll
        for (int i = 0; i < 4; ++i)
            #pragma unroll
            for (int j = 0; j < 4; ++j)
                acc[i][j] = __builtin_amdgcn_mfma_f32_16x16x32_f16(af[i], bf[j], acc[i][j], 0, 0, 0);
    }

    #pragma unroll
    for (int i = 0; i < 4; ++i) {
        const int row0 = m0 + wm + i * 16 + quad * 4;
        #pragma unroll
        for (int r = 0; r < 4; ++r) {
            float* orow = QT + (size_t)(row0 + r) * DIM + n0 + wn + l15;
            #pragma unroll
            for (int j = 0; j < 4; ++j)
                orow[j * 16] = acc[i][j][r];
        }
    }
}

// ---------------------------------------------------------------------------
// Banded attention, 16 queries per block. Templated on QT element type:
// f16 (fast path, QT in ws) or f32 (fallback, QT in d_out, in-place safe).
// ---------------------------------------------------------------------------
#define TQ  16
#define KP  64
#define KLD 80
#define QLD 80
#define SLD 66

template <typename QTT>
__global__ __launch_bounds__(256, 4) void attn_mfma(const QTT* __restrict__ QT,
                                                    const float* __restrict__ Keys,
                                                    float* __restrict__ Out) {
    const int blk  = blockIdx.x;
    const int b    = blk & 7;          // batch == XCD (8 XCDs): keys stay L2-local
    const int tile = blk >> 3;
    const int q0   = tile * TQ;
    const int t    = threadIdx.x;
    const int lane = t & 63;
    const int wv   = t >> 6;
    const int l15  = lane & 15;
    const int quad = lane >> 4;

    const int klo = (q0 - WIN) > 0 ? (q0 - WIN) : 0;
    const int khi = (q0 + TQ - 1 + WIN) < (SEQ - 1) ? (q0 + TQ - 1 + WIN) : (SEQ - 1);
    const int nk  = khi - klo + 1;     // <= 56

    const QTT*   qt   = QT + ((size_t)b * SEQ + q0) * DIM;
    const float* keys = Keys + (size_t)b * SEQ * DIM;

    __shared__ _Float16 Qc[TQ * QLD];
    __shared__ _Float16 Ks[KP * KLD];
    __shared__ float    Sl[TQ * SLD];
    __shared__ float    Wl[TQ * SLD];

    const int qr = t >> 4;             // 0..15 (q row)
    const int qc = (t & 15) * 4;       // 0..60
    const int kr = t >> 2;             // 0..63 (key row)
    const int kc = (t & 3) * 4;        // 0,4,8,12
    const int krow = (klo + kr) < (SEQ - 1) ? (klo + kr) : (SEQ - 1);

    const QTT*   qsrc = qt + (size_t)qr * DIM + qc;
    const float* ksrc = keys + (size_t)krow * DIM + kc;

    f32x4 acc_s = {};

    for (int d0 = 0; d0 < DIM; d0 += 64) {
        half4v hq;
        if constexpr (sizeof(QTT) == 2) {
            hq = *(const half4v*)(qsrc + d0);
        } else {
            const float4 qv = *(const float4*)(qsrc + d0);
            hq = half4v{(_Float16)qv.x, (_Float16)qv.y, (_Float16)qv.z, (_Float16)qv.w};
        }
        float4 kv0 = *(const float4*)(ksrc + d0);
        float4 kv1 = *(const float4*)(ksrc + d0 + 16);
        float4 kv2 = *(const float4*)(ksrc + d0 + 32);
        float4 kv3 = *(const float4*)(ksrc + d0 + 48);

        __syncthreads();   // previous iteration's fragment reads done

        *(half4v*)&Qc[qr * QLD + qc] = hq;
        half4v h0 = {(_Float16)kv0.x, (_Float16)kv0.y, (_Float16)kv0.z, (_Float16)kv0.w};
        half4v h1 = {(_Float16)kv1.x, (_Float16)kv1.y, (_Float16)kv1.z, (_Float16)kv1.w};
        half4v h2 = {(_Float16)kv2.x, (_Float16)kv2.y, (_Float16)kv2.z, (_Float16)kv2.w};
        half4v h3 = {(_Float16)kv3.x, (_Float16)kv3.y, (_Float16)kv3.z, (_Float16)kv3.w};
        *(half4v*)&Ks[kr * KLD + kc]      = h0;
        *(half4v*)&Ks[kr * KLD + kc + 16] = h1;
        *(half4v*)&Ks[kr * KLD + kc + 32] = h2;
        *(half4v*)&Ks[kr * KLD + kc + 48] = h3;

        __syncthreads();

        #pragma unroll
        for (int s = 0; s < 2; ++s) {
            half8 af = *(const half8*)&Qc[l15 * QLD + s * 32 + quad * 8];
            half8 bf = *(const half8*)&Ks[(wv * 16 + l15) * KLD + s * 32 + quad * 8];
            acc_s = __builtin_amdgcn_mfma_f32_16x16x32_f16(af, bf, acc_s, 0, 0, 0);
        }
    }

    // logits -> Sl with band mask. C layout: col=lane&15 (key), row=quad*4+reg (q).
    __syncthreads();
    #pragma unroll
    for (int r = 0; r < 4; ++r) {
        const int q = quad * 4 + r;
        const int c = wv * 16 + l15;
        const int d = (q0 + q) - (klo + c);
        const bool valid = (c < nk) && ((unsigned)(d + WIN) <= 2u * WIN);
        Sl[q * SLD + c] = valid ? acc_s[r] : -1e30f;
    }
    __syncthreads();

    // softmax: wave 0, 4 lanes per q-row, 16 cols per lane
    if (t < 64) {
        const int q = t >> 2, part = t & 3;
        const float* srow = &Sl[q * SLD + part * 16];
        float*       wrow = &Wl[q * SLD + part * 16];
        float m = -1e30f;
        #pragma unroll
        for (int i = 0; i < 16; ++i) m = fmaxf(m, srow[i]);
        m = fmaxf(m, __shfl_xor(m, 1));
        m = fmaxf(m, __shfl_xor(m, 2));
        float ssum = 0.f;
        #pragma unroll
        for (int i = 0; i < 16; ++i) { float e = expf(srow[i] - m); wrow[i] = e; ssum += e; }
        ssum += __shfl_xor(ssum, 1);
        ssum += __shfl_xor(ssum, 2);
        const float inv = 1.f / ssum;
        #pragma unroll
        for (int i = 0; i < 16; ++i) wrow[i] *= inv;
    }
    __syncthreads();

    // PV: thread t owns d-cols {t, t+256, t+512, t+768}; fp32 keys from global.
    float accs[TQ][4] = {};
    for (int c = 0; c < nk; ++c) {
        const float* krow2 = keys + (size_t)(klo + c) * DIM;
        const float k0 = krow2[t], k1 = krow2[t + 256], k2 = krow2[t + 512], k3 = krow2[t + 768];
        #pragma unroll
        for (int q = 0; q < TQ; ++q) {
            const float w = Wl[q * SLD + c];   // same addr across lanes: broadcast
            accs[q][0] = fmaf(w, k0, accs[q][0]);
            accs[q][1] = fmaf(w, k1, accs[q][1]);
            accs[q][2] = fmaf(w, k2, accs[q][2]);
            accs[q][3] = fmaf(w, k3, accs[q][3]);
        }
    }
    #pragma unroll
    for (int q = 0; q < TQ; ++q) {
        float* orow = Out + ((size_t)b * SEQ + q0 + q) * DIM;
        orow[t]       = accs[q][0];
        orow[t + 256] = accs[q][1];
        orow[t + 512] = accs[q][2];
        orow[t + 768] = accs[q][3];
    }
}

extern "C" void kernel_launch(void* const* d_in, const int* in_sizes, int n_in,
                              void* d_out, int out_size, void* d_ws, size_t ws_size,
                              hipStream_t stream) {
    const float* queries = (const float*)d_in[0];
    const float* keys    = (const float*)d_in[1];
    const float* W       = (const float*)d_in[2];
    // d_in[3] (b_reduce): constant over k within a row -> cancels in softmax.
    float* out = (float*)d_out;

    const size_t qt16_bytes = (size_t)BATCH * SEQ * DIM * sizeof(_Float16);  // 33.5 MB
    const size_t w16_bytes  = (size_t)DIM * DIM * sizeof(_Float16);          //  2.0 MB
    const int nblk = (BATCH * SEQ) / TQ;   // 1024

    if (ws_size >= qt16_bytes + w16_bytes) {
        // Fast path. Q16 lives in d_out (dead until attn overwrites it);
        // QT16 + W16T live in the workspace.
        _Float16* q16  = (_Float16*)d_out;
        _Float16* qt16 = (_Float16*)d_ws;
        _Float16* w16t = (_Float16*)((char*)d_ws + qt16_bytes);

        cvt_q_f16<<<2048, 256, 0, stream>>>(queries, q16);
        cvt_w_t<<<dim3(16, 16), 256, 0, stream>>>(W, w16t);
        gemm_f16t<<<dim3(128, 8), 256, 0, stream>>>(q16, w16t, qt16);
        attn_mfma<_Float16><<<nblk, 256, 0, stream>>>(qt16, keys, out);
    } else {
        // Fallback: R3 path, fp32 QT through d_out, in-place attn.
        gemm_qw_f16<<<dim3(128, 8), 256, 0, stream>>>(queries, W, out);
        attn_mfma<float><<<nblk, 256, 0, stream>>>(out, keys, out);
    }
}